// Round 9
// baseline (267.527 us; speedup 1.0000x reference)
//
#include <hip/hip_runtime.h>
#include <hip/hip_bf16.h>

typedef float    f4v    __attribute__((ext_vector_type(4)));
typedef short    short8 __attribute__((ext_vector_type(8)));
typedef unsigned u2v    __attribute__((ext_vector_type(2)));

constexpr int Bn = 4096, TR = 16;

// ---- split-bf16 helpers ----------------------------------------------------
__device__ inline unsigned cvt2(float x, float y) {
  union { __hip_bfloat162 h; unsigned u; } c;
  c.h = __float22bfloat162_rn(float2{x, y});
  return c.u;   // low16 = bf16(x), high16 = bf16(y)
}
__device__ inline void split_pair(float x, float y, unsigned& hp, unsigned& lp) {
  hp = cvt2(x, y);
  float hx = __uint_as_float(hp << 16);
  float hy = __uint_as_float(hp & 0xffff0000u);
  lp = cvt2(x - hx, y - hy);
}
union S8U { unsigned u[4]; short8 s; };
__device__ inline void split8(const float v[8], short8& hi, short8& lo) {
  S8U h, l;
  #pragma unroll
  for (int d = 0; d < 4; ++d) split_pair(v[2 * d], v[2 * d + 1], h.u[d], l.u[d]);
  hi = h.s; lo = l.s;
}
__device__ inline void split8p(const float* p, short8& hi, short8& lo) {
  f4v a = *(const f4v*)p, b = *(const f4v*)(p + 4);
  float v[8] = {a[0], a[1], a[2], a[3], b[0], b[1], b[2], b[3]};
  split8(v, hi, lo);
}
__device__ inline f4v mfma16(short8 a, short8 b, f4v c) {
  return __builtin_amdgcn_mfma_f32_16x16x32_bf16(a, b, c, 0, 0, 0);
}
__device__ __attribute__((always_inline)) inline f4v gdot8(
    const short8 (&ah)[8], const short8 (&al)[8],
    const short8 (&bh)[8], const short8 (&bl)[8]) {
  f4v c = {0.f, 0.f, 0.f, 0.f};
  #pragma unroll
  for (int s = 0; s < 8; ++s) {
    c = mfma16(ah[s], bh[s], c);
    c = mfma16(al[s], bh[s], c);
    c = mfma16(ah[s], bl[s], c);
  }
  return c;
}

// ---------------------------------------------------------------------------
// k_prep (1 block, 1024 thr):
//   KAT[n][m] = ((AA^T+eps I)^-1 A)^T  -> d_ws[0..8192)
//   NT[n][j]  = (I - A^T KA)^T[n][j] = delta(n,j) - sum_m KAT[n][m] A[m][j]
//             -> d_ws[8192..73728)
// ---------------------------------------------------------------------------
__global__ __launch_bounds__(1024) void k_prep(const float* __restrict__ A,
                                               float* __restrict__ KAT,
                                               float* __restrict__ NT) {
  __shared__ __align__(16) float As[8192];     // A 32x256
  __shared__ float Gm[32 * 68];                // [G | I] augmented
  __shared__ float GinvL[1024];                // Ginv 32x32
  __shared__ __align__(16) float KATs[8192];   // KAT 256x32

  const int t = threadIdx.x;
  const int lane = t & 63, wv = t >> 6, quad = lane >> 4, l15 = lane & 15;

  for (int i = t; i < 2048; i += 1024) ((f4v*)As)[i] = ((const f4v*)A)[i];
  __syncthreads();

  // ---- G = A A^T (+eps I) via split-bf16 MFMA on waves 0-3 ----
  if (wv < 4) {
    const int T = wv & 1, kh = wv >> 1;
    short8 afh[2][8], afl[2][8];
    #pragma unroll
    for (int tt = 0; tt < 2; ++tt)
      #pragma unroll
      for (int s = 0; s < 8; ++s)
        split8p(As + (l15 + 16 * tt) * 256 + 32 * s + 8 * quad,
                afh[tt][s], afl[tt][s]);
    f4v cg;
    if      (wv == 0) cg = gdot8(afh[0], afl[0], afh[0], afl[0]);
    else if (wv == 1) cg = gdot8(afh[1], afl[1], afh[0], afl[0]);
    else if (wv == 2) cg = gdot8(afh[0], afl[0], afh[1], afl[1]);
    else              cg = gdot8(afh[1], afl[1], afh[1], afl[1]);
    #pragma unroll
    for (int r = 0; r < 4; ++r) {
      int gi = 16 * T + 4 * quad + r, gj = 16 * kh + l15;
      Gm[gi * 68 + gj]      = cg[r] + (gi == gj ? 1e-6f : 0.f);
      Gm[gi * 68 + 32 + gj] = (gi == gj) ? 1.f : 0.f;
    }
  }
  __syncthreads();

  // ---- Gauss-Jordan on wave 0 (lane = augmented column, shuffles only) ----
  if (wv == 0) {
    float gcol[32];
    #pragma unroll
    for (int i = 0; i < 32; ++i) gcol[i] = Gm[i * 68 + lane];
    #pragma unroll
    for (int k = 0; k < 32; ++k) {
      float ckk  = __shfl(gcol[k], k);
      float ipiv = 1.f / ckk;
      float pivj = gcol[k] * ipiv;
      gcol[k] = pivj;
      #pragma unroll
      for (int i = 0; i < 32; ++i) {
        if (i == k) continue;
        float cki = __shfl(gcol[i], k);
        gcol[i] = fmaf(-cki, pivj, gcol[i]);
      }
    }
    if (lane >= 32) {
      #pragma unroll
      for (int i = 0; i < 32; ++i) GinvL[i * 32 + (lane - 32)] = gcol[i];
    }
  }
  __syncthreads();

  // ---- KAT row t = sum_p As[p][t] * Ginv[p][*]  (threads 0..255) ----
  if (t < 256) {
    float res[32];
    #pragma unroll
    for (int m = 0; m < 32; ++m) res[m] = 0.f;
    for (int p = 0; p < 32; ++p) {
      float av = As[p * 256 + t];
      #pragma unroll
      for (int m4 = 0; m4 < 8; ++m4) {
        f4v g = *(const f4v*)&GinvL[p * 32 + 4 * m4];
        res[4 * m4 + 0] = fmaf(av, g[0], res[4 * m4 + 0]);
        res[4 * m4 + 1] = fmaf(av, g[1], res[4 * m4 + 1]);
        res[4 * m4 + 2] = fmaf(av, g[2], res[4 * m4 + 2]);
        res[4 * m4 + 3] = fmaf(av, g[3], res[4 * m4 + 3]);
      }
    }
    #pragma unroll
    for (int m4 = 0; m4 < 8; ++m4) {
      f4v v = {res[4 * m4], res[4 * m4 + 1], res[4 * m4 + 2], res[4 * m4 + 3]};
      *(f4v*)&KATs[t * 32 + 4 * m4] = v;
      *(f4v*)&KAT[t * 32 + 4 * m4]  = v;
    }
  }
  __syncthreads();

  // ---- NT = I - KAT @ A via MFMA: wave wv owns row-tile tn = wv ----
  {
    short8 kth, ktl;
    {
      float v[8];
      #pragma unroll
      for (int j = 0; j < 8; ++j) v[j] = KATs[(16 * wv + l15) * 32 + 8 * quad + j];
      split8(v, kth, ktl);
    }
    for (int tj = 0; tj < 16; ++tj) {
      float v[8];
      #pragma unroll
      for (int jj = 0; jj < 8; ++jj)
        v[jj] = As[(8 * quad + jj) * 256 + 16 * tj + l15];
      short8 bsh, bsl;
      split8(v, bsh, bsl);
      f4v cg = {0.f, 0.f, 0.f, 0.f};
      cg = mfma16(kth, bsh, cg);
      cg = mfma16(ktl, bsh, cg);
      cg = mfma16(kth, bsl, cg);
      #pragma unroll
      for (int r = 0; r < 4; ++r) {
        int n = 16 * wv + 4 * quad + r, col = 16 * tj + l15;
        NT[(size_t)n * 256 + col] = (n == col ? 1.f : 0.f) - cg[r];
      }
    }
  }
}

// ---------------------------------------------------------------------------
// k_main: 512 threads (8 waves), TR=16, grid 256. Single-phase iteration:
//   u^T = NT z^T + c^T  (C-layout == zr register layout), update in regs,
//   publish z to double-buffered zfrag in B-op fragment order.
// ONE barrier per iteration; all 8 waves do identical work (2 U-tiles each).
// ---------------------------------------------------------------------------
__global__ __launch_bounds__(512, 2) void k_main(
    const float* __restrict__ x,  const float* __restrict__ bmat,
    const float* __restrict__ W1, const float* __restrict__ b1,
    const float* __restrict__ W2, const float* __restrict__ b2,
    const float* __restrict__ W3, const float* __restrict__ b3,
    const float* __restrict__ KAT, const float* __restrict__ NT,
    const int* __restrict__ n_iter_p, float* __restrict__ out) {

  __shared__ __align__(16) float    ubuf[8768];      // MLP scratch; later y[16][260]
  __shared__ __align__(16) unsigned zfrag[2][4096];  // dbuf: [s=0..7][hi/lo][1KB]

  const int t = threadIdx.x;
  const int lane = t & 63, wv = t >> 6, quad = lane >> 4, l15 = lane & 15;
  const int row0 = blockIdx.x * TR;

  float* xs = ubuf;            // [16][132]
  float* h1 = ubuf + 2112;     // [16][208]
  float* h2 = ubuf + 5440;     // [16][208]
  float* ys = ubuf;            // [16][260] (xs+h1 dead by then)

  {
    int r = t >> 5, c4 = t & 31;
    *(f4v*)&xs[r * 132 + 4 * c4] = *(const f4v*)&x[(size_t)(row0 + r) * 128 + 4 * c4];
  }
  __syncthreads();

  // ---- MLP: 2 rows per wave ----
  {
    const int rg = wv, oc = lane;
    const bool g3 = (oc < 8);    // HID=200: col oc+192 valid iff oc<8
    float acc[4][2];

    // L1: 128 -> 200, relu
    #pragma unroll
    for (int oi = 0; oi < 4; ++oi) { acc[oi][0] = 0.f; acc[oi][1] = 0.f; }
    for (int k4 = 0; k4 < 32; ++k4) {
      f4v xv0 = *(const f4v*)&xs[(2 * rg + 0) * 132 + 4 * k4];
      f4v xv1 = *(const f4v*)&xs[(2 * rg + 1) * 132 + 4 * k4];
      #pragma unroll
      for (int kk = 0; kk < 4; ++kk) {
        const float* wr = W1 + (4 * k4 + kk) * 200 + oc;
        float w0 = wr[0], w1c = wr[64], w2c = wr[128];
        float w3c = g3 ? wr[192] : 0.f;
        acc[0][0] = fmaf(xv0[kk], w0, acc[0][0]);  acc[0][1] = fmaf(xv1[kk], w0, acc[0][1]);
        acc[1][0] = fmaf(xv0[kk], w1c, acc[1][0]); acc[1][1] = fmaf(xv1[kk], w1c, acc[1][1]);
        acc[2][0] = fmaf(xv0[kk], w2c, acc[2][0]); acc[2][1] = fmaf(xv1[kk], w2c, acc[2][1]);
        acc[3][0] = fmaf(xv0[kk], w3c, acc[3][0]); acc[3][1] = fmaf(xv1[kk], w3c, acc[3][1]);
      }
    }
    #pragma unroll
    for (int oi = 0; oi < 4; ++oi) {
      if (oi == 3 && !g3) continue;
      float bb = b1[oc + 64 * oi];
      h1[(2 * rg + 0) * 208 + oc + 64 * oi] = fmaxf(acc[oi][0] + bb, 0.f);
      h1[(2 * rg + 1) * 208 + oc + 64 * oi] = fmaxf(acc[oi][1] + bb, 0.f);
    }
    __syncthreads();

    // L2: 200 -> 200, relu
    #pragma unroll
    for (int oi = 0; oi < 4; ++oi) { acc[oi][0] = 0.f; acc[oi][1] = 0.f; }
    for (int k4 = 0; k4 < 50; ++k4) {
      f4v xv0 = *(const f4v*)&h1[(2 * rg + 0) * 208 + 4 * k4];
      f4v xv1 = *(const f4v*)&h1[(2 * rg + 1) * 208 + 4 * k4];
      #pragma unroll
      for (int kk = 0; kk < 4; ++kk) {
        const float* wr = W2 + (4 * k4 + kk) * 200 + oc;
        float w0 = wr[0], w1c = wr[64], w2c = wr[128];
        float w3c = g3 ? wr[192] : 0.f;
        acc[0][0] = fmaf(xv0[kk], w0, acc[0][0]);  acc[0][1] = fmaf(xv1[kk], w0, acc[0][1]);
        acc[1][0] = fmaf(xv0[kk], w1c, acc[1][0]); acc[1][1] = fmaf(xv1[kk], w1c, acc[1][1]);
        acc[2][0] = fmaf(xv0[kk], w2c, acc[2][0]); acc[2][1] = fmaf(xv1[kk], w2c, acc[2][1]);
        acc[3][0] = fmaf(xv0[kk], w3c, acc[3][0]); acc[3][1] = fmaf(xv1[kk], w3c, acc[3][1]);
      }
    }
    #pragma unroll
    for (int oi = 0; oi < 4; ++oi) {
      if (oi == 3 && !g3) continue;
      float bb = b2[oc + 64 * oi];
      h2[(2 * rg + 0) * 208 + oc + 64 * oi] = fmaxf(acc[oi][0] + bb, 0.f);
      h2[(2 * rg + 1) * 208 + oc + 64 * oi] = fmaxf(acc[oi][1] + bb, 0.f);
    }
    __syncthreads();

    // L3: 200 -> 256 (no relu) -> ys
    #pragma unroll
    for (int oi = 0; oi < 4; ++oi) { acc[oi][0] = 0.f; acc[oi][1] = 0.f; }
    for (int k4 = 0; k4 < 50; ++k4) {
      f4v xv0 = *(const f4v*)&h2[(2 * rg + 0) * 208 + 4 * k4];
      f4v xv1 = *(const f4v*)&h2[(2 * rg + 1) * 208 + 4 * k4];
      #pragma unroll
      for (int kk = 0; kk < 4; ++kk) {
        const float* wr = W3 + (4 * k4 + kk) * 256 + oc;
        float w0 = wr[0], w1c = wr[64], w2c = wr[128], w3c = wr[192];
        acc[0][0] = fmaf(xv0[kk], w0, acc[0][0]);  acc[0][1] = fmaf(xv1[kk], w0, acc[0][1]);
        acc[1][0] = fmaf(xv0[kk], w1c, acc[1][0]); acc[1][1] = fmaf(xv1[kk], w1c, acc[1][1]);
        acc[2][0] = fmaf(xv0[kk], w2c, acc[2][0]); acc[2][1] = fmaf(xv1[kk], w2c, acc[2][1]);
        acc[3][0] = fmaf(xv0[kk], w3c, acc[3][0]); acc[3][1] = fmaf(xv1[kk], w3c, acc[3][1]);
      }
    }
    __syncthreads();   // reads of h2/xs done before ys overlays ubuf
    #pragma unroll
    for (int oi = 0; oi < 4; ++oi) {
      float bb = b3[oc + 64 * oi];
      ys[(2 * rg + 0) * 260 + oc + 64 * oi] = acc[oi][0] + bb;
      ys[(2 * rg + 1) * 260 + oc + 64 * oi] = acc[oi][1] + bb;
    }
  }
  __syncthreads();

  // ---- c^T = (b @ KA)^T for this block's rows (C-layout == zr layout) ----
  f4v cvec[2];
  {
    short8 bfh, bfl;
    {
      float v[8];
      #pragma unroll
      for (int j = 0; j < 8; ++j)
        v[j] = bmat[(size_t)(row0 + l15) * 32 + 8 * quad + j];
      split8(v, bfh, bfl);
    }
    #pragma unroll
    for (int u = 0; u < 2; ++u) {
      const int U = 2 * wv + u;
      short8 kh_, kl_;
      {
        float v[8];
        #pragma unroll
        for (int j = 0; j < 8; ++j)
          v[j] = KAT[(size_t)(16 * U + l15) * 32 + 8 * quad + j];
        split8(v, kh_, kl_);
      }
      f4v cc = {0.f, 0.f, 0.f, 0.f};
      cc = mfma16(kh_, bfh, cc);
      cc = mfma16(kl_, bfh, cc);
      cc = mfma16(kh_, bfl, cc);
      cvec[u] = cc;
    }
  }

  // ---- invariant NT A-op fragments: 2 U-tiles x 8 k-steps (hi/lo) ----
  short8 nth[2][8], ntl[2][8];
  #pragma unroll
  for (int u = 0; u < 2; ++u) {
    const int U = 2 * wv + u;
    #pragma unroll
    for (int s = 0; s < 8; ++s) {
      float v[8];
      #pragma unroll
      for (int j = 0; j < 8; ++j)
        v[j] = NT[(size_t)(16 * U + l15) * 256 + 32 * s + 8 * quad + j];
      split8(v, nth[u][s], ntl[u][s]);
    }
  }

  // ---- zfrag write offsets (B-op fragment order, derived from U) ----
  int zoff[2];
  #pragma unroll
  for (int u = 0; u < 2; ++u) {
    const int U = 2 * wv + u;
    const int qp = 2 * (U & 1) + (quad >> 1);
    zoff[u] = (((U >> 3) * 4 + ((U >> 1) & 3)) * 2) * 256
              + qp * 64 + l15 * 4 + 2 * (quad & 1);
  }

  // ---- init z registers from y; publish zfrag[0] ----
  float zr[2][4];
  #pragma unroll
  for (int u = 0; u < 2; ++u) {
    const int U = 2 * wv + u;
    f4v yv = *(const f4v*)&ys[l15 * 260 + 16 * U + 4 * quad];
    #pragma unroll
    for (int r = 0; r < 4; ++r) zr[u][r] = yv[r];
    unsigned h0, l0, h1_, l1_;
    split_pair(zr[u][0], zr[u][1], h0, l0);
    split_pair(zr[u][2], zr[u][3], h1_, l1_);
    u2v hv; hv[0] = h0; hv[1] = h1_;
    u2v lv; lv[0] = l0; lv[1] = l1_;
    *(u2v*)&zfrag[0][zoff[u]] = hv;
    *(u2v*)&zfrag[0][zoff[u] + 256] = lv;
  }
  __syncthreads();

  const int niter = n_iter_p[0];
  int p = 0;

  for (int it = 0; it <= niter; ++it) {
    const unsigned* zb = zfrag[p];
    f4v a0[2], a1[2];
    a0[0] = cvec[0]; a0[1] = cvec[1];
    a1[0] = f4v{0.f, 0.f, 0.f, 0.f};
    a1[1] = f4v{0.f, 0.f, 0.f, 0.f};
    #pragma unroll
    for (int s = 0; s < 8; ++s) {
      short8 zh = *(const short8*)&zb[(2 * s + 0) * 256 + lane * 4];
      short8 zl = *(const short8*)&zb[(2 * s + 1) * 256 + lane * 4];
      #pragma unroll
      for (int u = 0; u < 2; ++u) {
        f4v acc = (s & 1) ? a1[u] : a0[u];
        acc = mfma16(nth[u][s], zh, acc);
        acc = mfma16(ntl[u][s], zh, acc);
        acc = mfma16(nth[u][s], zl, acc);
        if (s & 1) a1[u] = acc; else a0[u] = acc;
      }
    }

    if (it < niter) {
      unsigned* zw = zfrag[p ^ 1];
      #pragma unroll
      for (int u = 0; u < 2; ++u) {
        f4v uu = a0[u] + a1[u];                    // u = p_aff(z), this tile
        #pragma unroll
        for (int r = 0; r < 4; ++r) {
          float z = zr[u][r], uv = uu[r];
          float vv = fminf(fmaxf(2.f * uv - z, 0.f), 1.f);  // clip(2u - z)
          zr[u][r] = fmaf(1.7f, vv - uv, z);                // z += 1.7*(v-u)
        }
        unsigned h0, l0, h1_, l1_;
        split_pair(zr[u][0], zr[u][1], h0, l0);
        split_pair(zr[u][2], zr[u][3], h1_, l1_);
        u2v hv; hv[0] = h0; hv[1] = h1_;
        u2v lv; lv[0] = l0; lv[1] = l1_;
        *(u2v*)&zw[zoff[u]] = hv;
        *(u2v*)&zw[zoff[u] + 256] = lv;
      }
      __syncthreads();
      p ^= 1;
    } else {
      #pragma unroll
      for (int u = 0; u < 2; ++u) {
        const int U = 2 * wv + u;
        f4v ov = a0[u] + a1[u];                    // out = p_aff(z_final)
        *(f4v*)&out[(size_t)(row0 + l15) * 256 + 16 * U + 4 * quad] = ov;
      }
    }
  }
}

// ---------------------------------------------------------------------------
extern "C" void kernel_launch(void* const* d_in, const int* in_sizes, int n_in,
                              void* d_out, int out_size, void* d_ws, size_t ws_size,
                              hipStream_t stream) {
  const float* x    = (const float*)d_in[0];
  const float* bmat = (const float*)d_in[1];
  const float* W1   = (const float*)d_in[2];
  const float* b1   = (const float*)d_in[3];
  const float* W2   = (const float*)d_in[4];
  const float* b2   = (const float*)d_in[5];
  const float* W3   = (const float*)d_in[6];
  const float* b3   = (const float*)d_in[7];
  const float* A    = (const float*)d_in[8];
  const int*  n_it  = (const int*)d_in[10];
  float* KAT = (float*)d_ws;                  // 256*32  floats = 32 KB
  float* NT  = (float*)d_ws + 8192;           // 256*256 floats = 256 KB
  float* out = (float*)d_out;

  hipLaunchKernelGGL(k_prep, dim3(1), dim3(1024), 0, stream, A, KAT, NT);
  hipLaunchKernelGGL(k_main, dim3(Bn / TR), dim3(512), 0, stream,
                     x, bmat, W1, b1, W2, b2, W3, b3, KAT, NT, n_it, out);
}